// Round 7
// baseline (543.869 us; speedup 1.0000x reference)
//
#include <hip/hip_runtime.h>
#include <hip/hip_bf16.h>
#include <math.h>

#define NN 50000
#define EE 800000
// NF=128, EF=64, S=128; NN/16 = 3125 row-tiles exactly; EE/256 = 3125

typedef __bf16 bf16x8 __attribute__((ext_vector_type(8)));
typedef float f32x4 __attribute__((ext_vector_type(4)));
typedef unsigned int u32x4 __attribute__((ext_vector_type(4)));

// ---------------- fused0: 4 independent roles in one dispatch, role-striped ----------------
// odd blocks:  v=B>>1 < 2048 -> per-edge GEMM (writes out[e]=c+b0; no aArr/bArr dep)
//              v < 2816      -> GEMM1 (xs unscaled; dinv applied in gather)
//              else idle (437 blocks, exit immediately)
// even blocks: v < 3125      -> deg histogram (atomic-latency pipe)
//              else          -> weight prep (v-3125 in [0,128))
// Striping keeps HBM/MFMA-bound edge+g1 waves co-resident with the atomic-bound
// histogram waves for the whole dispatch (blocks launch in blockIdx order).
#define GRID0 6506
__global__ __launch_bounds__(256) void k_fused0(const int* __restrict__ ei, int* __restrict__ deg,
                            const float* __restrict__ Wzc, const float* __restrict__ bzc,
                            const float* __restrict__ Wzl, const float* __restrict__ bzl,
                            const float* __restrict__ Whc, const float* __restrict__ bhc,
                            const float* __restrict__ Whl, const float* __restrict__ bhl,
                            float* __restrict__ Wcat, float* __restrict__ cb,
                            const float* __restrict__ x, const float* __restrict__ Wn,
                            const float* __restrict__ bn, __hip_bfloat16* __restrict__ xs,
                            const float* __restrict__ EA, const float* __restrict__ We,
                            const float* __restrict__ be, const float* __restrict__ Wout,
                            const float* __restrict__ boutp, float* __restrict__ out) {
    const unsigned B = blockIdx.x;
    const unsigned v = B >> 1;
    if (B & 1u) {
        if (v < 2048) {
            // ---- per-edge GEMM: out[e] = relu(ea@We+be) . Wout[256:] + b0 ----
            const int lane = threadIdx.x & 63;
            const int ln = lane & 15;
            const int q  = lane >> 4;
            const int wid = v * 4 + (threadIdx.x >> 6);   // [0, 8192)
            const int nw  = 8192;

            bf16x8 bfrag[2][8];
#pragma unroll
            for (int h = 0; h < 2; h++)
#pragma unroll
                for (int t = 0; t < 8; t++)
#pragma unroll
                    for (int j = 0; j < 8; j++)
                        bfrag[h][t][j] = (__bf16)We[(h * 32 + q * 8 + j) * 128 + t * 16 + ln];

            float beR[8], w3R[8];
#pragma unroll
            for (int t = 0; t < 8; t++) {
                beR[t] = be[t * 16 + ln];
                w3R[t] = Wout[256 + t * 16 + ln];
            }
            const float b0 = boutp[0];

            for (int tile = wid; tile < EE / 16; tile += nw) {
                const int e0 = tile * 16;
                const float* arow = EA + (size_t)(e0 + ln) * 64;
                float4 v0 = *(const float4*)(arow + q * 8);
                float4 v1 = *(const float4*)(arow + q * 8 + 4);
                float4 v2 = *(const float4*)(arow + 32 + q * 8);
                float4 v3 = *(const float4*)(arow + 32 + q * 8 + 4);
                bf16x8 af0, af1;
                af0[0] = (__bf16)v0.x; af0[1] = (__bf16)v0.y; af0[2] = (__bf16)v0.z; af0[3] = (__bf16)v0.w;
                af0[4] = (__bf16)v1.x; af0[5] = (__bf16)v1.y; af0[6] = (__bf16)v1.z; af0[7] = (__bf16)v1.w;
                af1[0] = (__bf16)v2.x; af1[1] = (__bf16)v2.y; af1[2] = (__bf16)v2.z; af1[3] = (__bf16)v2.w;
                af1[4] = (__bf16)v3.x; af1[5] = (__bf16)v3.y; af1[6] = (__bf16)v3.z; af1[7] = (__bf16)v3.w;

                f32x4 acc[8];
#pragma unroll
                for (int t = 0; t < 8; t++) acc[t] = (f32x4){0.f, 0.f, 0.f, 0.f};
#pragma unroll
                for (int t = 0; t < 8; t++)
                    acc[t] = __builtin_amdgcn_mfma_f32_16x16x32_bf16(af0, bfrag[0][t], acc[t], 0, 0, 0);
#pragma unroll
                for (int t = 0; t < 8; t++)
                    acc[t] = __builtin_amdgcn_mfma_f32_16x16x32_bf16(af1, bfrag[1][t], acc[t], 0, 0, 0);

                float part[4] = {0.f, 0.f, 0.f, 0.f};
#pragma unroll
                for (int t = 0; t < 8; t++)
#pragma unroll
                    for (int r = 0; r < 4; r++) {
                        float y = acc[t][r] + beR[t];
                        y = fmaxf(y, 0.f);
                        part[r] += y * w3R[t];
                    }
#pragma unroll
                for (int off = 1; off < 16; off <<= 1) {
#pragma unroll
                    for (int r = 0; r < 4; r++) part[r] += __shfl_xor(part[r], off);
                }
                if (ln < 4) {
                    float c = (ln == 0) ? part[0] : (ln == 1) ? part[1] : (ln == 2) ? part[2] : part[3];
                    out[e0 + q * 4 + ln] = c + b0;
                }
            }
        } else if (v < 2816) {
            // ---- GEMM1: xs[N,128] = bf16( relu(x @ Wn + bn) ) (unscaled) ----
            const int lane = threadIdx.x & 63;
            const int ln = lane & 15;
            const int q  = lane >> 4;
            const int wid = (int)(v - 2048) * 4 + (threadIdx.x >> 6);   // [0, 3072)
            const int nw  = 3072;
            const int ch  = wid & 1;
            const int step = nw >> 1;

            bf16x8 bfrag[4][4];
#pragma unroll
            for (int t = 0; t < 4; t++)
#pragma unroll
                for (int kc = 0; kc < 4; kc++)
#pragma unroll
                    for (int j = 0; j < 8; j++)
                        bfrag[t][kc][j] = (__bf16)Wn[(kc * 32 + q * 8 + j) * 128 + ch * 64 + t * 16 + ln];
            float biasR[4];
#pragma unroll
            for (int t = 0; t < 4; t++) biasR[t] = bn[ch * 64 + t * 16 + ln];

            for (int rt = wid >> 1; rt < 3125; rt += step) {
                const int e0 = rt * 16;
                const float* arow = x + (size_t)(e0 + ln) * 128;
                bf16x8 af[4];
#pragma unroll
                for (int kc = 0; kc < 4; kc++) {
                    float4 v0 = *(const float4*)(arow + kc * 32 + q * 8);
                    float4 v1 = *(const float4*)(arow + kc * 32 + q * 8 + 4);
                    af[kc][0] = (__bf16)v0.x; af[kc][1] = (__bf16)v0.y;
                    af[kc][2] = (__bf16)v0.z; af[kc][3] = (__bf16)v0.w;
                    af[kc][4] = (__bf16)v1.x; af[kc][5] = (__bf16)v1.y;
                    af[kc][6] = (__bf16)v1.z; af[kc][7] = (__bf16)v1.w;
                }
                f32x4 acc[4];
#pragma unroll
                for (int t = 0; t < 4; t++) acc[t] = (f32x4){0.f, 0.f, 0.f, 0.f};
#pragma unroll
                for (int t = 0; t < 4; t++)
#pragma unroll
                    for (int kc = 0; kc < 4; kc++)
                        acc[t] = __builtin_amdgcn_mfma_f32_16x16x32_bf16(af[kc], bfrag[t][kc], acc[t], 0, 0, 0);
#pragma unroll
                for (int t = 0; t < 4; t++)
#pragma unroll
                    for (int r = 0; r < 4; r++) {
                        float vv = fmaxf(acc[t][r] + biasR[t], 0.f);
                        xs[(size_t)(e0 + q * 4 + r) * 128 + ch * 64 + t * 16 + ln] = __float2bfloat16(vv);
                    }
            }
        }
        // else: idle odd block, exit
    } else {
        if (v < 3125) {
            // ---- deg histogram ----
            int e = (int)v * 256 + threadIdx.x;
            if (e < EE) atomicAdd(&deg[ei[EE + e]], 1);
        } else {
            // ---- weight prep ----
            int i = (int)v - 3125;   // [0,128)
            int k = threadIdx.x;
            if (k < 128) {
                float sz = 0.f, sh = 0.f;
                for (int j = 0; j < 128; j++) {
                    sz += Wzc[i * 128 + j] * Wzl[j * 128 + k];
                    sh += Whc[i * 128 + j] * Whl[j * 128 + k];
                }
                Wcat[i * 256 + 2 * k]     = sz;
                Wcat[i * 256 + 2 * k + 1] = sh;
                if (i == 0) {
                    float bz = bzl[k], bh = bhl[k];
                    for (int j = 0; j < 128; j++) {
                        bz += bzc[j] * Wzl[j * 128 + k];
                        bh += bhc[j] * Whl[j * 128 + k];
                    }
                    cb[2 * k]     = bz;
                    cb[2 * k + 1] = bh;
                }
            }
        }
    }
}

// ---------------- scan: pass A (block partials) ----------------
__global__ void k_scan_a(const int* __restrict__ deg, int* __restrict__ partial) {
    __shared__ int s[256];
    int i = blockIdx.x * 256 + threadIdx.x;
    s[threadIdx.x] = (i < NN) ? deg[i] : 0;
    __syncthreads();
    for (int off = 128; off > 0; off >>= 1) {
        if (threadIdx.x < off) s[threadIdx.x] += s[threadIdx.x + off];
        __syncthreads();
    }
    if (threadIdx.x == 0) partial[blockIdx.x] = s[0];
}

// ---------------- scan: pass C (per-block base + local scan); also emits dinvArr ----------------
__global__ void k_scan_c(const int* __restrict__ deg, const int* __restrict__ partial,
                         int* __restrict__ rowptr, int* __restrict__ cursor,
                         float* __restrict__ dinvArr) {
    __shared__ int s[256];
    __shared__ int ps[256];
    int i = blockIdx.x * 256 + threadIdx.x;
    int v = (i < NN) ? deg[i] : 0;
    s[threadIdx.x] = v;
    ps[threadIdx.x] = (threadIdx.x < blockIdx.x) ? partial[threadIdx.x] : 0;  // nb=196<=256
    __syncthreads();
    // reduce ps -> block base in ps[0]
    for (int off = 128; off > 0; off >>= 1) {
        if (threadIdx.x < off) ps[threadIdx.x] += ps[threadIdx.x + off];
        __syncthreads();
    }
    // inclusive scan of s
    for (int off = 1; off < 256; off <<= 1) {
        int t = (threadIdx.x >= off) ? s[threadIdx.x - off] : 0;
        __syncthreads();
        s[threadIdx.x] += t;
        __syncthreads();
    }
    int excl = s[threadIdx.x] - v + ps[0];
    if (i < NN) {
        rowptr[i] = excl; cursor[i] = excl;
        dinvArr[i] = rsqrtf((float)(v + 1));
    }
    if (i == 0) rowptr[NN] = EE;
}

__global__ void k_fill(const int* __restrict__ ei, int* __restrict__ cursor,
                       int* __restrict__ col) {
    int e = blockIdx.x * 256 + threadIdx.x;
    if (e < EE) {
        int d = ei[EE + e];
        int p = atomicAdd(&cursor[d], 1);
        col[p] = ei[e];
    }
}

// ---------------- per-node gather, lane-group dwordx4, per-src dinv fma ----------------
__global__ __launch_bounds__(256) void k_gather(const unsigned int* __restrict__ xsu,
                                                const int* __restrict__ rowptr,
                                                const int* __restrict__ col,
                                                const float* __restrict__ dinvArr,
                                                unsigned int* __restrict__ aggu) {
    int gt = blockIdx.x * 256 + threadIdx.x;
    int node = gt >> 6;
    int lane = threadIdx.x & 63;
    if (node >= NN) return;
    const int g = lane >> 4;      // neighbor sub-slot within a chunk of 4
    const int k = lane & 15;      // dword-quad index within a row (dwords 4k..4k+3)
    int beg = rowptr[node], end = rowptr[node + 1];
    const float dn = dinvArr[node];

    float acc[8];
#pragma unroll
    for (int i = 0; i < 8; i++) acc[i] = 0.f;

    // self loop: group 0 only
    {
        u32x4 sv = *(const u32x4*)(xsu + (size_t)node * 64 + k * 4);
        if (g == 0) {
#pragma unroll
            for (int d = 0; d < 4; d++) {
                acc[2 * d]     += dn * __uint_as_float(sv[d] << 16);
                acc[2 * d + 1] += dn * __uint_as_float(sv[d] & 0xFFFF0000u);
            }
        }
    }

    int p = beg;
    while (p < end) {
        int rem = end - p;
        int chunk = rem < 64 ? rem : 64;
        int cv = (lane < chunk) ? col[p + lane] : 0;
        for (int j = 0; j < chunk; j += 4) {
            int s = __shfl(cv, j + g);
            float dv = dinvArr[s];
            u32x4 v = *(const u32x4*)(xsu + (size_t)s * 64 + k * 4);
            if (j + g >= chunk) v = (u32x4){0u, 0u, 0u, 0u};
#pragma unroll
            for (int d = 0; d < 4; d++) {
                acc[2 * d]     += dv * __uint_as_float(v[d] << 16);
                acc[2 * d + 1] += dv * __uint_as_float(v[d] & 0xFFFF0000u);
            }
        }
        p += 64;
    }

#pragma unroll
    for (int off = 16; off < 64; off <<= 1)
#pragma unroll
        for (int i = 0; i < 8; i++) acc[i] += __shfl_xor(acc[i], off);

    unsigned int o0, o1, o2, o3;
    {
        __hip_bfloat16 lo, hi;
        lo = __float2bfloat16(acc[0] * dn); hi = __float2bfloat16(acc[1] * dn);
        o0 = (unsigned int)*(unsigned short*)&lo | ((unsigned int)*(unsigned short*)&hi << 16);
        lo = __float2bfloat16(acc[2] * dn); hi = __float2bfloat16(acc[3] * dn);
        o1 = (unsigned int)*(unsigned short*)&lo | ((unsigned int)*(unsigned short*)&hi << 16);
        lo = __float2bfloat16(acc[4] * dn); hi = __float2bfloat16(acc[5] * dn);
        o2 = (unsigned int)*(unsigned short*)&lo | ((unsigned int)*(unsigned short*)&hi << 16);
        lo = __float2bfloat16(acc[6] * dn); hi = __float2bfloat16(acc[7] * dn);
        o3 = (unsigned int)*(unsigned short*)&lo | ((unsigned int)*(unsigned short*)&hi << 16);
    }
    int src = lane >> 2;
    unsigned int t0 = __shfl((int)o0, src);
    unsigned int t1 = __shfl((int)o1, src);
    unsigned int t2 = __shfl((int)o2, src);
    unsigned int t3 = __shfl((int)o3, src);
    int c2 = lane & 3;
    unsigned int res = (c2 == 0) ? t0 : (c2 == 1) ? t1 : (c2 == 2) ? t2 : t3;
    aggu[(size_t)node * 64 + lane] = res;
}

// ---------------- gate GEMM via MFMA + gates + projection, atomic-free ----------------
__global__ __launch_bounds__(256) void k_gate_red(const unsigned int* __restrict__ aggu,
                                                  const float* __restrict__ Wcat,
                                                  const float* __restrict__ cb,
                                                  const float* __restrict__ Wout,
                                                  float* __restrict__ aArr,
                                                  float* __restrict__ bArr) {
    __shared__ float red[4][32];
    const int lane = threadIdx.x & 63;
    const int ln = lane & 15;
    const int q  = lane >> 4;
    const int w  = threadIdx.x >> 6;   // wave id == column quarter

    bf16x8 bfrag[4][4];
#pragma unroll
    for (int t = 0; t < 4; t++)
#pragma unroll
        for (int kc = 0; kc < 4; kc++)
#pragma unroll
            for (int j = 0; j < 8; j++)
                bfrag[t][kc][j] = (__bf16)Wcat[(kc * 32 + q * 8 + j) * 256 + w * 64 + t * 16 + ln];

    float cbR[4], wAR[4], wBR[4];
#pragma unroll
    for (int t = 0; t < 4; t++) {
        int c = w * 64 + t * 16 + ln;
        cbR[t] = cb[c];
        int k = c >> 1;
        wAR[t] = Wout[k];
        wBR[t] = Wout[128 + k];
    }
    const bool odd = (ln & 1);

    for (int rt = blockIdx.x; rt < 3125; rt += gridDim.x) {
        const int e0 = rt * 16;
        const u32x4* arow = (const u32x4*)aggu + (size_t)(e0 + ln) * 16;
        bf16x8 af[4];
#pragma unroll
        for (int kc = 0; kc < 4; kc++) {
            u32x4 uv = arow[kc * 4 + q];
            af[kc] = __builtin_bit_cast(bf16x8, uv);
        }
        f32x4 acc[4];
#pragma unroll
        for (int t = 0; t < 4; t++) acc[t] = (f32x4){0.f, 0.f, 0.f, 0.f};
#pragma unroll
        for (int t = 0; t < 4; t++)
#pragma unroll
            for (int kc = 0; kc < 4; kc++)
                acc[t] = __builtin_amdgcn_mfma_f32_16x16x32_bf16(af[kc], bfrag[t][kc], acc[t], 0, 0, 0);

        float pa[4] = {0.f, 0.f, 0.f, 0.f};
        float pb[4] = {0.f, 0.f, 0.f, 0.f};
#pragma unroll
        for (int t = 0; t < 4; t++)
#pragma unroll
            for (int r = 0; r < 4; r++) {
                float val = acc[t][r] + cbR[t];
                float s = odd ? tanhf(val) : (1.f / (1.f + expf(-val)));
                float partner = __shfl_xor(s, 1);
                if (!odd) {
                    float h = (1.f - s) * partner;   // (1-z)*tanh(t)
                    pa[r] += h * wAR[t];
                    pb[r] += h * wBR[t];
                }
            }
#pragma unroll
        for (int off = 1; off < 16; off <<= 1) {
#pragma unroll
            for (int r = 0; r < 4; r++) {
                pa[r] += __shfl_xor(pa[r], off);
                pb[r] += __shfl_xor(pb[r], off);
            }
        }
        if (ln < 4) {
            float v = (ln == 0) ? pa[0] : (ln == 1) ? pa[1] : (ln == 2) ? pa[2] : pa[3];
            red[w][q * 4 + ln] = v;
        } else if (ln < 8) {
            int r = ln - 4;
            float v = (r == 0) ? pb[0] : (r == 1) ? pb[1] : (r == 2) ? pb[2] : pb[3];
            red[w][16 + q * 4 + r] = v;
        }
        __syncthreads();
        if (threadIdx.x < 32) {
            int row = threadIdx.x & 15;
            int ab = threadIdx.x >> 4;
            float s = red[0][ab * 16 + row] + red[1][ab * 16 + row]
                    + red[2][ab * 16 + row] + red[3][ab * 16 + row];
            if (ab) bArr[e0 + row] = s; else aArr[e0 + row] = s;
        }
        __syncthreads();
    }
}

// ---------------- tail: out[e] += aArr[src] + bArr[dst] ----------------
__global__ void k_edge_add(const int* __restrict__ ei,
                           const float* __restrict__ aArr,
                           const float* __restrict__ bArr,
                           float* __restrict__ out) {
    int e = blockIdx.x * 256 + threadIdx.x;
    if (e < EE) out[e] += aArr[ei[e]] + bArr[ei[EE + e]];
}

extern "C" void kernel_launch(void* const* d_in, const int* in_sizes, int n_in,
                              void* d_out, int out_size, void* d_ws, size_t ws_size,
                              hipStream_t stream) {
    const float* x    = (const float*)d_in[0];
    const int*   ei   = (const int*)d_in[1];
    const float* ea   = (const float*)d_in[2];
    const float* Wn   = (const float*)d_in[3];
    const float* bn   = (const float*)d_in[4];
    const float* We   = (const float*)d_in[5];
    const float* be   = (const float*)d_in[6];
    const float* Wzc  = (const float*)d_in[7];
    const float* bzc  = (const float*)d_in[8];
    const float* Wzl  = (const float*)d_in[9];
    const float* bzl  = (const float*)d_in[10];
    const float* Whc  = (const float*)d_in[15];
    const float* bhc  = (const float*)d_in[16];
    const float* Whl  = (const float*)d_in[17];
    const float* bhl  = (const float*)d_in[18];
    const float* Wout = (const float*)d_in[19];
    const float* bout = (const float*)d_in[20];
    float* out = (float*)d_out;

    char* w = (char*)d_ws;
    auto carve = [&](size_t bytes) {
        void* p = (void*)w;
        w += (bytes + 255) / 256 * 256;
        return p;
    };
    int*   deg     = (int*)carve((size_t)NN * 4);
    float* aArr    = (float*)carve((size_t)NN * 4);   // plain stores (no zero-init needed)
    float* bArr    = (float*)carve((size_t)NN * 4);
    float* dinvArr = (float*)carve((size_t)NN * 4);
    __hip_bfloat16* xs = (__hip_bfloat16*)carve((size_t)NN * 128 * 2);
    unsigned int* aggu = (unsigned int*)carve((size_t)NN * 64 * 4);
    float* Wcat    = (float*)carve(128 * 256 * 4);
    float* cb      = (float*)carve(256 * 4);
    int*   rowptr  = (int*)carve((size_t)(NN + 1) * 4);
    int*   cursor  = (int*)carve((size_t)NN * 4);
    int*   col     = (int*)carve((size_t)EE * 4);
    int*   partial = (int*)carve(256 * 4);

    hipMemsetAsync(deg, 0, (size_t)NN * 4, stream);

    // weight prep + deg histogram + GEMM1 + edge-GEMM-partial, role-striped, ONE dispatch
    k_fused0<<<GRID0, 256, 0, stream>>>(ei, deg, Wzc, bzc, Wzl, bzl,
                                        Whc, bhc, Whl, bhl, Wcat, cb,
                                        x, Wn, bn, xs,
                                        ea, We, be, Wout, bout, out);

    // CSR build (2-pass scan + fill); scan_c also emits dinvArr
    const int NB = (NN + 255) / 256;  // 196
    k_scan_a<<<NB, 256, 0, stream>>>(deg, partial);
    k_scan_c<<<NB, 256, 0, stream>>>(deg, partial, rowptr, cursor, dinvArr);
    k_fill<<<3125, 256, 0, stream>>>(ei, cursor, col);

    // agg (packed bf16) = dinv[n] * ( dinv[n]*xs[n] + sum dinv[s]*xs[s] )
    k_gather<<<(NN * 64 + 255) / 256, 256, 0, stream>>>((const unsigned int*)xs, rowptr, col, dinvArr, aggu);

    // gates + projection, atomic-free (LDS cross-wave reduce, plain stores)
    k_gate_red<<<512, 256, 0, stream>>>(aggu, Wcat, cb, Wout, aArr, bArr);

    // tail: add node contributions to the precomputed edge partials
    k_edge_add<<<3125, 256, 0, stream>>>(ei, aArr, bArr, out);
}

// Round 8
// 512.809 us; speedup vs baseline: 1.0606x; 1.0606x over previous
//
#include <hip/hip_runtime.h>
#include <hip/hip_bf16.h>
#include <math.h>

#define NN 50000
#define EE 800000
// NF=128, EF=64, S=128; NN/16 = 3125 row-tiles exactly; EE/256 = 3125

typedef __bf16 bf16x8 __attribute__((ext_vector_type(8)));
typedef float f32x4 __attribute__((ext_vector_type(4)));
typedef unsigned int u32x4 __attribute__((ext_vector_type(4)));

// ---------------- fused: weight prep (blocks 0..127) + deg histogram (128..3252) + GEMM1 (>=3253) ----
// The three ranges are independent: g1 no longer reads deg (dinv scaling moved to the
// gather via dinvArr), so the MFMA-heavy g1 waves overlap the atomic-latency-bound
// histogram waves on separate pipes within one dispatch.
#define G1B 3253   // first g1 block
__global__ __launch_bounds__(256) void k_fused0(const int* __restrict__ ei, int* __restrict__ deg,
                            const float* __restrict__ Wzc, const float* __restrict__ bzc,
                            const float* __restrict__ Wzl, const float* __restrict__ bzl,
                            const float* __restrict__ Whc, const float* __restrict__ bhc,
                            const float* __restrict__ Whl, const float* __restrict__ bhl,
                            float* __restrict__ Wcat, float* __restrict__ cb,
                            const float* __restrict__ x, const float* __restrict__ Wn,
                            const float* __restrict__ bn, __hip_bfloat16* __restrict__ xs) {
    if (blockIdx.x < 128) {
        int i = blockIdx.x;      // fan-in row (uniform -> scalar loads of Wzc/Whc)
        int k = threadIdx.x;     // out col (coalesced over Wzl/Whl)
        if (k < 128) {
            float sz = 0.f, sh = 0.f;
            for (int j = 0; j < 128; j++) {
                sz += Wzc[i * 128 + j] * Wzl[j * 128 + k];
                sh += Whc[i * 128 + j] * Whl[j * 128 + k];
            }
            Wcat[i * 256 + 2 * k]     = sz;
            Wcat[i * 256 + 2 * k + 1] = sh;
            if (i == 0) {
                float bz = bzl[k], bh = bhl[k];
                for (int j = 0; j < 128; j++) {
                    bz += bzc[j] * Wzl[j * 128 + k];
                    bh += bhc[j] * Whl[j * 128 + k];
                }
                cb[2 * k]     = bz;
                cb[2 * k + 1] = bh;
            }
        }
    } else if (blockIdx.x < G1B) {
        int e = (blockIdx.x - 128) * 256 + threadIdx.x;
        if (e < EE) atomicAdd(&deg[ei[EE + e]], 1);
    } else {
        // ---- GEMM1: xs[N,128] = bf16( relu(x @ Wn + bn) )  (UNSCALED; dinv applied in gather) ----
        const int lane = threadIdx.x & 63;
        const int ln = lane & 15;
        const int q  = lane >> 4;
        const int wid = ((blockIdx.x - G1B) * 256 + threadIdx.x) >> 6;
        const int nw  = (gridDim.x - G1B) * 4;
        const int ch  = wid & 1;          // column half
        const int step = nw >> 1;

        bf16x8 bfrag[4][4];               // [t][kc]: B[k=kc*32+q*8+j][col=ch*64+t*16+ln]
#pragma unroll
        for (int t = 0; t < 4; t++)
#pragma unroll
            for (int kc = 0; kc < 4; kc++)
#pragma unroll
                for (int j = 0; j < 8; j++)
                    bfrag[t][kc][j] = (__bf16)Wn[(kc * 32 + q * 8 + j) * 128 + ch * 64 + t * 16 + ln];
        float biasR[4];
#pragma unroll
        for (int t = 0; t < 4; t++) biasR[t] = bn[ch * 64 + t * 16 + ln];

        for (int rt = wid >> 1; rt < 3125; rt += step) {
            const int e0 = rt * 16;
            const float* arow = x + (size_t)(e0 + ln) * 128;
            bf16x8 af[4];
#pragma unroll
            for (int kc = 0; kc < 4; kc++) {
                float4 v0 = *(const float4*)(arow + kc * 32 + q * 8);
                float4 v1 = *(const float4*)(arow + kc * 32 + q * 8 + 4);
                af[kc][0] = (__bf16)v0.x; af[kc][1] = (__bf16)v0.y;
                af[kc][2] = (__bf16)v0.z; af[kc][3] = (__bf16)v0.w;
                af[kc][4] = (__bf16)v1.x; af[kc][5] = (__bf16)v1.y;
                af[kc][6] = (__bf16)v1.z; af[kc][7] = (__bf16)v1.w;
            }
            f32x4 acc[4];
#pragma unroll
            for (int t = 0; t < 4; t++) acc[t] = (f32x4){0.f, 0.f, 0.f, 0.f};
#pragma unroll
            for (int t = 0; t < 4; t++)
#pragma unroll
                for (int kc = 0; kc < 4; kc++)
                    acc[t] = __builtin_amdgcn_mfma_f32_16x16x32_bf16(af[kc], bfrag[t][kc], acc[t], 0, 0, 0);
#pragma unroll
            for (int t = 0; t < 4; t++)
#pragma unroll
                for (int r = 0; r < 4; r++) {
                    float v = fmaxf(acc[t][r] + biasR[t], 0.f);
                    xs[(size_t)(e0 + q * 4 + r) * 128 + ch * 64 + t * 16 + ln] = __float2bfloat16(v);
                }
        }
    }
}

// ---------------- scan: pass A (block partials) ----------------
__global__ void k_scan_a(const int* __restrict__ deg, int* __restrict__ partial) {
    __shared__ int s[256];
    int i = blockIdx.x * 256 + threadIdx.x;
    s[threadIdx.x] = (i < NN) ? deg[i] : 0;
    __syncthreads();
    for (int off = 128; off > 0; off >>= 1) {
        if (threadIdx.x < off) s[threadIdx.x] += s[threadIdx.x + off];
        __syncthreads();
    }
    if (threadIdx.x == 0) partial[blockIdx.x] = s[0];
}

// ---------------- scan: pass C (per-block base + local scan); also emits dinvArr ----------------
__global__ void k_scan_c(const int* __restrict__ deg, const int* __restrict__ partial,
                         int* __restrict__ rowptr, int* __restrict__ cursor,
                         float* __restrict__ dinvArr) {
    __shared__ int s[256];
    __shared__ int ps[256];
    int i = blockIdx.x * 256 + threadIdx.x;
    int v = (i < NN) ? deg[i] : 0;
    s[threadIdx.x] = v;
    ps[threadIdx.x] = (threadIdx.x < blockIdx.x) ? partial[threadIdx.x] : 0;  // nb=196<=256
    __syncthreads();
    // reduce ps -> block base in ps[0]
    for (int off = 128; off > 0; off >>= 1) {
        if (threadIdx.x < off) ps[threadIdx.x] += ps[threadIdx.x + off];
        __syncthreads();
    }
    // inclusive scan of s
    for (int off = 1; off < 256; off <<= 1) {
        int t = (threadIdx.x >= off) ? s[threadIdx.x - off] : 0;
        __syncthreads();
        s[threadIdx.x] += t;
        __syncthreads();
    }
    int excl = s[threadIdx.x] - v + ps[0];
    if (i < NN) {
        rowptr[i] = excl; cursor[i] = excl;
        dinvArr[i] = rsqrtf((float)(v + 1));
    }
    if (i == 0) rowptr[NN] = EE;
}

__global__ void k_fill(const int* __restrict__ ei, int* __restrict__ cursor,
                       int* __restrict__ col) {
    int e = blockIdx.x * 256 + threadIdx.x;
    if (e < EE) {
        int d = ei[EE + e];
        int p = atomicAdd(&cursor[d], 1);
        col[p] = ei[e];
    }
}

// ---------------- per-node gather, lane-group dwordx4, per-src dinv fma ----------------
// One wave per node. 4 groups of 16 lanes; group g reads neighbor (j+g)'s row as
// 16 lanes x 16B. agg = dinv[node] * ( dinv[node]*xs[node] + sum dinv[s]*xs[s] ).
__global__ __launch_bounds__(256) void k_gather(const unsigned int* __restrict__ xsu,
                                                const int* __restrict__ rowptr,
                                                const int* __restrict__ col,
                                                const float* __restrict__ dinvArr,
                                                unsigned int* __restrict__ aggu) {
    int gt = blockIdx.x * 256 + threadIdx.x;
    int node = gt >> 6;
    int lane = threadIdx.x & 63;
    if (node >= NN) return;
    const int g = lane >> 4;      // neighbor sub-slot within a chunk of 4
    const int k = lane & 15;      // dword-quad index within a row (dwords 4k..4k+3)
    int beg = rowptr[node], end = rowptr[node + 1];
    const float dn = dinvArr[node];

    float acc[8];
#pragma unroll
    for (int i = 0; i < 8; i++) acc[i] = 0.f;

    // self loop: group 0 only (other groups would quadruple it after the reduce)
    {
        u32x4 sv = *(const u32x4*)(xsu + (size_t)node * 64 + k * 4);
        if (g == 0) {
#pragma unroll
            for (int d = 0; d < 4; d++) {
                acc[2 * d]     += dn * __uint_as_float(sv[d] << 16);
                acc[2 * d + 1] += dn * __uint_as_float(sv[d] & 0xFFFF0000u);
            }
        }
    }

    int p = beg;
    while (p < end) {
        int rem = end - p;
        int chunk = rem < 64 ? rem : 64;
        int cv = (lane < chunk) ? col[p + lane] : 0;
        for (int j = 0; j < chunk; j += 4) {
            int s = __shfl(cv, j + g);                 // per-lane src (16-lane broadcast)
            float dv = dinvArr[s];
            u32x4 v = *(const u32x4*)(xsu + (size_t)s * 64 + k * 4);
            if (j + g >= chunk) v = (u32x4){0u, 0u, 0u, 0u};
#pragma unroll
            for (int d = 0; d < 4; d++) {
                acc[2 * d]     += dv * __uint_as_float(v[d] << 16);
                acc[2 * d + 1] += dv * __uint_as_float(v[d] & 0xFFFF0000u);
            }
        }
        p += 64;
    }

    // reduce the 4 groups (lanes k, k+16, k+32, k+48 hold the same columns)
#pragma unroll
    for (int off = 16; off < 64; off <<= 1)
#pragma unroll
        for (int i = 0; i < 8; i++) acc[i] += __shfl_xor(acc[i], off);

    // pack: this lane holds output dwords 4k..4k+3
    unsigned int o0, o1, o2, o3;
    {
        __hip_bfloat16 lo, hi;
        lo = __float2bfloat16(acc[0] * dn); hi = __float2bfloat16(acc[1] * dn);
        o0 = (unsigned int)*(unsigned short*)&lo | ((unsigned int)*(unsigned short*)&hi << 16);
        lo = __float2bfloat16(acc[2] * dn); hi = __float2bfloat16(acc[3] * dn);
        o1 = (unsigned int)*(unsigned short*)&lo | ((unsigned int)*(unsigned short*)&hi << 16);
        lo = __float2bfloat16(acc[4] * dn); hi = __float2bfloat16(acc[5] * dn);
        o2 = (unsigned int)*(unsigned short*)&lo | ((unsigned int)*(unsigned short*)&hi << 16);
        lo = __float2bfloat16(acc[6] * dn); hi = __float2bfloat16(acc[7] * dn);
        o3 = (unsigned int)*(unsigned short*)&lo | ((unsigned int)*(unsigned short*)&hi << 16);
    }
    // redistribute: lane l wants dword l, held by lane l>>2 as component l&3
    int src = lane >> 2;
    unsigned int t0 = __shfl((int)o0, src);
    unsigned int t1 = __shfl((int)o1, src);
    unsigned int t2 = __shfl((int)o2, src);
    unsigned int t3 = __shfl((int)o3, src);
    int c2 = lane & 3;
    unsigned int res = (c2 == 0) ? t0 : (c2 == 1) ? t1 : (c2 == 2) ? t2 : t3;
    aggu[(size_t)node * 64 + lane] = res;
}

// ---------------- gate GEMM via MFMA + gates + projection, atomic-free ----------------
__global__ __launch_bounds__(256) void k_gate_red(const unsigned int* __restrict__ aggu,
                                                  const float* __restrict__ Wcat,
                                                  const float* __restrict__ cb,
                                                  const float* __restrict__ Wout,
                                                  float* __restrict__ aArr,
                                                  float* __restrict__ bArr) {
    __shared__ float red[4][32];
    const int lane = threadIdx.x & 63;
    const int ln = lane & 15;
    const int q  = lane >> 4;
    const int w  = threadIdx.x >> 6;   // wave id == column quarter

    bf16x8 bfrag[4][4];               // [t][kc]: Wcat[k=kc*32+q*8+j][col=w*64+t*16+ln]
#pragma unroll
    for (int t = 0; t < 4; t++)
#pragma unroll
        for (int kc = 0; kc < 4; kc++)
#pragma unroll
            for (int j = 0; j < 8; j++)
                bfrag[t][kc][j] = (__bf16)Wcat[(kc * 32 + q * 8 + j) * 256 + w * 64 + t * 16 + ln];

    float cbR[4], wAR[4], wBR[4];
#pragma unroll
    for (int t = 0; t < 4; t++) {
        int c = w * 64 + t * 16 + ln;
        cbR[t] = cb[c];
        int k = c >> 1;               // meaningful on even lanes only
        wAR[t] = Wout[k];
        wBR[t] = Wout[128 + k];
    }
    const bool odd = (ln & 1);

    for (int rt = blockIdx.x; rt < 3125; rt += gridDim.x) {
        const int e0 = rt * 16;
        const u32x4* arow = (const u32x4*)aggu + (size_t)(e0 + ln) * 16;
        bf16x8 af[4];
#pragma unroll
        for (int kc = 0; kc < 4; kc++) {
            u32x4 uv = arow[kc * 4 + q];
            af[kc] = __builtin_bit_cast(bf16x8, uv);
        }
        f32x4 acc[4];
#pragma unroll
        for (int t = 0; t < 4; t++) acc[t] = (f32x4){0.f, 0.f, 0.f, 0.f};
#pragma unroll
        for (int t = 0; t < 4; t++)
#pragma unroll
            for (int kc = 0; kc < 4; kc++)
                acc[t] = __builtin_amdgcn_mfma_f32_16x16x32_bf16(af[kc], bfrag[t][kc], acc[t], 0, 0, 0);

        float pa[4] = {0.f, 0.f, 0.f, 0.f};
        float pb[4] = {0.f, 0.f, 0.f, 0.f};
#pragma unroll
        for (int t = 0; t < 4; t++)
#pragma unroll
            for (int r = 0; r < 4; r++) {
                float val = acc[t][r] + cbR[t];
                float s = odd ? tanhf(val) : (1.f / (1.f + expf(-val)));
                float partner = __shfl_xor(s, 1);
                if (!odd) {
                    float h = (1.f - s) * partner;   // (1-z)*tanh(t)
                    pa[r] += h * wAR[t];
                    pb[r] += h * wBR[t];
                }
            }
#pragma unroll
        for (int off = 1; off < 16; off <<= 1) {
#pragma unroll
            for (int r = 0; r < 4; r++) {
                pa[r] += __shfl_xor(pa[r], off);
                pb[r] += __shfl_xor(pb[r], off);
            }
        }
        if (ln < 4) {
            float v = (ln == 0) ? pa[0] : (ln == 1) ? pa[1] : (ln == 2) ? pa[2] : pa[3];
            red[w][q * 4 + ln] = v;
        } else if (ln < 8) {
            int r = ln - 4;
            float v = (r == 0) ? pb[0] : (r == 1) ? pb[1] : (r == 2) ? pb[2] : pb[3];
            red[w][16 + q * 4 + r] = v;
        }
        __syncthreads();   // red complete across the block's 4 waves
        if (threadIdx.x < 32) {
            int row = threadIdx.x & 15;
            int ab = threadIdx.x >> 4;
            float s = red[0][ab * 16 + row] + red[1][ab * 16 + row]
                    + red[2][ab * 16 + row] + red[3][ab * 16 + row];
            if (ab) bArr[e0 + row] = s; else aArr[e0 + row] = s;
        }
        __syncthreads();   // fence red reads before next iteration's red writes
    }
}

// ---------------- per-edge fused GEMM via MFMA ----------------
__global__ __launch_bounds__(256) void k_edge_mfma(const float* __restrict__ EA,
                                                   const int* __restrict__ ei,
                                                   const float* __restrict__ We,
                                                   const float* __restrict__ be,
                                                   const float* __restrict__ Wout,
                                                   const float* __restrict__ boutp,
                                                   const float* __restrict__ aArr,
                                                   const float* __restrict__ bArr,
                                                   float* __restrict__ out) {
    const int lane = threadIdx.x & 63;
    const int ln = lane & 15;
    const int q  = lane >> 4;
    const int wid = (blockIdx.x * 256 + threadIdx.x) >> 6;
    const int nw  = gridDim.x * 4;

    bf16x8 bfrag[2][8];
#pragma unroll
    for (int h = 0; h < 2; h++)
#pragma unroll
        for (int t = 0; t < 8; t++)
#pragma unroll
            for (int j = 0; j < 8; j++)
                bfrag[h][t][j] = (__bf16)We[(h * 32 + q * 8 + j) * 128 + t * 16 + ln];

    float beR[8], w3R[8];
#pragma unroll
    for (int t = 0; t < 8; t++) {
        beR[t] = be[t * 16 + ln];
        w3R[t] = Wout[256 + t * 16 + ln];
    }
    const float b0 = boutp[0];

    for (int tile = wid; tile < EE / 16; tile += nw) {
        const int e0 = tile * 16;
        const float* arow = EA + (size_t)(e0 + ln) * 64;
        float4 v0 = *(const float4*)(arow + q * 8);
        float4 v1 = *(const float4*)(arow + q * 8 + 4);
        float4 v2 = *(const float4*)(arow + 32 + q * 8);
        float4 v3 = *(const float4*)(arow + 32 + q * 8 + 4);
        bf16x8 af0, af1;
        af0[0] = (__bf16)v0.x; af0[1] = (__bf16)v0.y; af0[2] = (__bf16)v0.z; af0[3] = (__bf16)v0.w;
        af0[4] = (__bf16)v1.x; af0[5] = (__bf16)v1.y; af0[6] = (__bf16)v1.z; af0[7] = (__bf16)v1.w;
        af1[0] = (__bf16)v2.x; af1[1] = (__bf16)v2.y; af1[2] = (__bf16)v2.z; af1[3] = (__bf16)v2.w;
        af1[4] = (__bf16)v3.x; af1[5] = (__bf16)v3.y; af1[6] = (__bf16)v3.z; af1[7] = (__bf16)v3.w;

        f32x4 acc[8];
#pragma unroll
        for (int t = 0; t < 8; t++) acc[t] = (f32x4){0.f, 0.f, 0.f, 0.f};
#pragma unroll
        for (int t = 0; t < 8; t++)
            acc[t] = __builtin_amdgcn_mfma_f32_16x16x32_bf16(af0, bfrag[0][t], acc[t], 0, 0, 0);
#pragma unroll
        for (int t = 0; t < 8; t++)
            acc[t] = __builtin_amdgcn_mfma_f32_16x16x32_bf16(af1, bfrag[1][t], acc[t], 0, 0, 0);

        float part[4] = {0.f, 0.f, 0.f, 0.f};
#pragma unroll
        for (int t = 0; t < 8; t++)
#pragma unroll
            for (int r = 0; r < 4; r++) {
                float y = acc[t][r] + beR[t];
                y = fmaxf(y, 0.f);
                part[r] += y * w3R[t];
            }
#pragma unroll
        for (int off = 1; off < 16; off <<= 1) {
#pragma unroll
            for (int r = 0; r < 4; r++) part[r] += __shfl_xor(part[r], off);
        }
        if (ln < 4) {
            float c = (ln == 0) ? part[0] : (ln == 1) ? part[1] : (ln == 2) ? part[2] : part[3];
            int e = e0 + q * 4 + ln;
            out[e] = c + aArr[ei[e]] + bArr[ei[EE + e]] + b0;
        }
    }
}

extern "C" void kernel_launch(void* const* d_in, const int* in_sizes, int n_in,
                              void* d_out, int out_size, void* d_ws, size_t ws_size,
                              hipStream_t stream) {
    const float* x    = (const float*)d_in[0];
    const int*   ei   = (const int*)d_in[1];
    const float* ea   = (const float*)d_in[2];
    const float* Wn   = (const float*)d_in[3];
    const float* bn   = (const float*)d_in[4];
    const float* We   = (const float*)d_in[5];
    const float* be   = (const float*)d_in[6];
    const float* Wzc  = (const float*)d_in[7];
    const float* bzc  = (const float*)d_in[8];
    const float* Wzl  = (const float*)d_in[9];
    const float* bzl  = (const float*)d_in[10];
    const float* Whc  = (const float*)d_in[15];
    const float* bhc  = (const float*)d_in[16];
    const float* Whl  = (const float*)d_in[17];
    const float* bhl  = (const float*)d_in[18];
    const float* Wout = (const float*)d_in[19];
    const float* bout = (const float*)d_in[20];
    float* out = (float*)d_out;

    char* w = (char*)d_ws;
    auto carve = [&](size_t bytes) {
        void* p = (void*)w;
        w += (bytes + 255) / 256 * 256;
        return p;
    };
    int*   deg     = (int*)carve((size_t)NN * 4);
    float* aArr    = (float*)carve((size_t)NN * 4);   // plain stores (no zero-init needed)
    float* bArr    = (float*)carve((size_t)NN * 4);
    float* dinvArr = (float*)carve((size_t)NN * 4);
    __hip_bfloat16* xs = (__hip_bfloat16*)carve((size_t)NN * 128 * 2);
    unsigned int* aggu = (unsigned int*)carve((size_t)NN * 64 * 4);
    float* Wcat    = (float*)carve(128 * 256 * 4);
    float* cb      = (float*)carve(256 * 4);
    int*   rowptr  = (int*)carve((size_t)(NN + 1) * 4);
    int*   cursor  = (int*)carve((size_t)NN * 4);
    int*   col     = (int*)carve((size_t)EE * 4);
    int*   partial = (int*)carve(256 * 4);

    hipMemsetAsync(deg, 0, (size_t)NN * 4, stream);

    // weight prep + deg histogram + GEMM1 (unscaled xs) in ONE dispatch
    k_fused0<<<G1B + 768, 256, 0, stream>>>(ei, deg, Wzc, bzc, Wzl, bzl,
                                            Whc, bhc, Whl, bhl, Wcat, cb,
                                            x, Wn, bn, xs);

    // CSR build (2-pass scan + fill); scan_c also emits dinvArr
    const int NB = (NN + 255) / 256;  // 196
    k_scan_a<<<NB, 256, 0, stream>>>(deg, partial);
    k_scan_c<<<NB, 256, 0, stream>>>(deg, partial, rowptr, cursor, dinvArr);
    k_fill<<<3125, 256, 0, stream>>>(ei, cursor, col);

    // agg (packed bf16) = dinv[n] * ( dinv[n]*xs[n] + sum dinv[s]*xs[s] )
    k_gather<<<(NN * 64 + 255) / 256, 256, 0, stream>>>((const unsigned int*)xs, rowptr, col, dinvArr, aggu);

    // gates + projection, atomic-free (LDS cross-wave reduce, plain stores)
    k_gate_red<<<512, 256, 0, stream>>>(aggu, Wcat, cb, Wout, aArr, bArr);

    // per-edge fused output
    k_edge_mfma<<<2048, 256, 0, stream>>>(ea, ei, We, be, Wout, bout, aArr, bArr, out);
}